// Round 3
// baseline (30839.249 us; speedup 1.0000x reference)
//
#include <hip/hip_runtime.h>
#include <math.h>

#define BT 256
#define LT 256
#define KT 128
#define HT 256
#define NP 4
#define NG 64
#define NT 512
#define LOSS_IDX ((size_t)BT*LT*KT)
#define PRED_IDX (LOSS_IDX + 1)

typedef _Float16 h2 __attribute__((ext_vector_type(2)));
typedef _Float16 h8 __attribute__((ext_vector_type(8)));

__device__ __forceinline__ float fd2(h2 a, h2 b, float c){
#if __has_builtin(__builtin_amdgcn_fdot2)
  return __builtin_amdgcn_fdot2(a, b, c, false);
#else
  return c + (float)a[0]*(float)b[0] + (float)a[1]*(float)b[1];
#endif
}
__device__ __forceinline__ float dot8(h8 w, h8 a, float acc){
  acc = fd2(__builtin_shufflevector(w,w,0,1), __builtin_shufflevector(a,a,0,1), acc);
  acc = fd2(__builtin_shufflevector(w,w,2,3), __builtin_shufflevector(a,a,2,3), acc);
  acc = fd2(__builtin_shufflevector(w,w,4,5), __builtin_shufflevector(a,a,4,5), acc);
  acc = fd2(__builtin_shufflevector(w,w,6,7), __builtin_shufflevector(a,a,6,7), acc);
  return acc;
}
__device__ __forceinline__ float sigf(float v){ return 1.0f/(1.0f + __expf(-v)); }
__device__ __forceinline__ float tanh_fast(float v){
  float a = fminf(fabsf(v), 15.0f);
  float e2 = __expf(2.0f*a);
  float r = (e2 - 1.0f)/(e2 + 1.0f);
  return copysignf(r, v);
}

// pack rows into part-major, chunk-major f16: dst[((p*C + c)*Rp + jloc)*8 + e]
__global__ void pack_part(const float* __restrict__ src, _Float16* __restrict__ dst,
                          int D, int Rp, int C, int gated, int zero_diag, int total){
  int idx = blockIdx.x*256 + threadIdx.x;
  if (idx >= total) return;
  int jloc = idx % Rp;
  int c = (idx / Rp) % C;
  int p = idx / (Rp*C);
  int row;
  if (gated){ int gate = jloc >> 6; int u = jloc & 63; row = gate*HT + p*64 + u; }
  else row = p*Rp + jloc;
  #pragma unroll
  for (int e = 0; e < 8; ++e){
    float v = src[(size_t)row*D + c*8 + e];
    if (zero_diag && (c*8 + e) == row) v = 0.0f;
    dst[(size_t)idx*8 + e] = (_Float16)v;
  }
}

__global__ void gxd_kernel(const float* __restrict__ W_gx, float* __restrict__ gxd){
  int k = threadIdx.x;
  if (k < KT) gxd[k] = W_gx[k*KT + k];
}

__global__ void msum_kernel(const float* __restrict__ mask, float* __restrict__ msumInv){
  __shared__ float red[256];
  int t = blockIdx.x;
  float acc = 0.0f;
  for (int i = threadIdx.x; i < BT*KT; i += 256){
    int b = i >> 7, k = i & 127;
    acc += mask[((size_t)b*LT + t)*KT + k];
  }
  red[threadIdx.x] = acc; __syncthreads();
  for (int s = 128; s > 0; s >>= 1){
    if (threadIdx.x < s) red[threadIdx.x] += red[threadIdx.x + s];
    __syncthreads();
  }
  if (threadIdx.x == 0) msumInv[t] = 1.0f/(red[0] + 1e-5f);
}

struct __align__(16) SMem {
  float h32[4][64];
  float hs32[4][64];
  float xt32[4][32];
  float mt32[4][32];
  float xh32[4][32];
  float al32[4][32];
  float gh[192][5];     // pad 5: avoid 4-way bank conflict
  float gi[192][5];
  float bgh_l[64], bcomb_l[32], bhist_l[32], bfeat_l[32];
  float bih_l[192], bhh_l[192], wout_l[64];
  float bgx_l[128], gxd_l[128];
  float red[8];
  int rn[4];
  alignas(16) _Float16 deh[4][KT];
  alignas(16) _Float16 axch[4][2*KT];   // [gamma_x | m]
  alignas(16) _Float16 hsfull[4][HT];
  alignas(16) _Float16 xcfull[4][KT];
  alignas(16) _Float16 ccm[4][2*KT];    // [c_c | m]
};

__global__ __launch_bounds__(NT, 2) void rits_main(
    const float* __restrict__ x, const float* __restrict__ mask, const float* __restrict__ ts,
    const float* __restrict__ b_gh, const float* __restrict__ b_gx,
    const float* __restrict__ b_hist, const float* __restrict__ b_feat,
    const float* __restrict__ b_comb, const float* __restrict__ b_ih, const float* __restrict__ b_hh,
    const float* __restrict__ W_out, const float* __restrict__ b_out,
    const int* __restrict__ record_num,
    const h8* __restrict__ Pgh, const h8* __restrict__ Phist,
    const h8* __restrict__ Pfeat, const h8* __restrict__ Pcomb,
    const h8* __restrict__ Pih, const h8* __restrict__ Phh,
    const float* __restrict__ gxd, const float* __restrict__ msumInv,
    _Float16* __restrict__ hsbuf, _Float16* __restrict__ xcbuf, _Float16* __restrict__ ccbuf,
    float* __restrict__ predbuf, int* __restrict__ flags,
    float* __restrict__ out)
{
  __shared__ SMem s;
  const int tid = threadIdx.x;
  const int g = blockIdx.x & 63;
  const int p = blockIdx.x >> 6;
  const int b0 = g*4;

  _Float16* hsb = hsbuf + (size_t)g*(NP*4*64);  // [p][b][64]
  _Float16* xcb = xcbuf + (size_t)g*(NP*4*32);  // [p][b][32]
  _Float16* ccb = ccbuf + (size_t)g*(NP*4*32);
  float* prb = predbuf + (size_t)g*(NP*4);
  int* fl = flags + (size_t)g*16;               // [type 0..3][part]

  // ---- init ----
  if (tid < 256){ int b = tid & 3, u = tid >> 2; s.h32[b][u] = 0.0f; }
  if (tid < 64) s.bgh_l[tid] = b_gh[64*p + tid];
  if (tid < 32){
    s.bcomb_l[tid] = b_comb[32*p + tid];
    s.bhist_l[tid] = b_hist[32*p + tid];
    s.bfeat_l[tid] = b_feat[32*p + tid];
  }
  if (tid < 192){
    int gate = tid / 64, u = tid % 64;
    s.bih_l[tid] = b_ih[gate*HT + 64*p + u];
    s.bhh_l[tid] = b_hh[gate*HT + 64*p + u];
  }
  if (tid >= 192 && tid < 256) s.wout_l[tid - 192] = W_out[64*p + (tid - 192)];
  if (tid >= 256 && tid < 384){ int k = tid - 256; s.bgx_l[k] = b_gx[k]; s.gxd_l[k] = gxd[k]; }
  if (tid < 4) s.rn[tid] = record_num[b0 + tid];
  __syncthreads();

  const int eb = tid >> 7, ek = tid & 127;     // A-phase (b,k)
  float dcr = 1.0f;
  float tprev = ts[(size_t)(b0 + eb)*LT];
  float loss = 0.0f;

  for (int t = 0; t < LT; ++t){
    const int tag = t + 1;

    // ---- A: elementwise, all 512 threads ----
    {
      size_t xoff = ((size_t)(b0 + eb)*LT + t)*KT + ek;
      float xv = x[xoff], mv = mask[xoff];
      float dv;
      if (t == 0){ dv = 1.0f; }
      else {
        float tsc = ts[(size_t)(b0 + eb)*LT + t];
        dv = fabsf(tsc - tprev) + (1.0f - mv)*dcr;
        tprev = tsc;
      }
      dcr = dv;
      float e = (t < s.rn[eb]) ? 1.0f : 0.0f;
      float dev = dv * e;
      s.deh[eb][ek] = (_Float16)dev;
      float gx = __expf(-fmaxf(fmaf(dev, s.gxd_l[ek], s.bgx_l[ek]), 0.0f));
      s.axch[eb][ek] = (_Float16)gx;
      s.axch[eb][KT + ek] = (_Float16)mv;
      s.ccm[eb][KT + ek] = (_Float16)mv;
      int kl = ek - 32*p;
      if (kl >= 0 && kl < 32){ s.xt32[eb][kl] = xv; s.mt32[eb][kl] = mv; }
    }
    __syncthreads();

    // ---- B: M1 gamma_h->hs (tid<256) ; M4 alpha (256..384) ----
    if (tid < 256){
      int jloc = tid >> 2, b = tid & 3;
      float acc = 0.0f;
      #pragma unroll 4
      for (int c = 0; c < 16; ++c){
        h8 w = Pgh[(p*16 + c)*64 + jloc];
        h8 av = *(const h8*)&s.deh[b][c*8];
        acc = dot8(w, av, acc);
      }
      float gv = __expf(-fmaxf(acc + s.bgh_l[jloc], 0.0f));
      float hsv = s.h32[b][jloc] * gv;
      s.hs32[b][jloc] = hsv;
      hsb[(p*4 + b)*64 + jloc] = (_Float16)hsv;
    } else if (tid < 384){
      int i = tid - 256, jloc = i >> 2, b = i & 3;
      float acc = 0.0f;
      #pragma unroll 4
      for (int c = 0; c < 32; ++c){
        h8 w = Pcomb[(p*32 + c)*32 + jloc];
        h8 av = *(const h8*)&s.axch[b][c*8];
        acc = dot8(w, av, acc);
      }
      s.al32[b][jloc] = acc + s.bcomb_l[jloc];
    }
    __threadfence();
    __syncthreads();
    if (tid == 0) __hip_atomic_store(&fl[0*NP + p], tag, __ATOMIC_RELEASE, __HIP_MEMORY_SCOPE_AGENT);
    if (tid < NP){
      int cnt = 0;
      while (__hip_atomic_load(&fl[0*NP + tid], __ATOMIC_ACQUIRE, __HIP_MEMORY_SCOPE_AGENT) < tag
             && ++cnt < (1 << 27)) {}
    }
    __syncthreads();
    { // assemble hsfull: 512 dwords
      unsigned int v = ((const unsigned int*)hsb)[tid];
      int p2 = tid >> 7, b = (tid >> 5) & 3, qd = tid & 31;
      *(unsigned int*)&s.hsfull[b][64*p2 + 2*qd] = v;
    }
    __syncthreads();

    // ---- C: M6 gh (tid<384) ; M2 x_h (384..512) ----
    if (tid < 384){
      int jr = tid >> 1, bh = tid & 1;
      int bA = 2*bh, bB = 2*bh + 1;
      float a0 = 0.0f, a1 = 0.0f;
      #pragma unroll 4
      for (int c = 0; c < 32; ++c){
        h8 w = Phh[(p*32 + c)*192 + jr];
        h8 v0 = *(const h8*)&s.hsfull[bA][c*8];
        h8 v1 = *(const h8*)&s.hsfull[bB][c*8];
        a0 = dot8(w, v0, a0); a1 = dot8(w, v1, a1);
      }
      s.gh[jr][bA] = a0; s.gh[jr][bB] = a1;
    } else {
      int i = tid - 384, jloc = i >> 2, b = i & 3;
      float acc = 0.0f;
      #pragma unroll 4
      for (int c = 0; c < 32; ++c){
        h8 w = Phist[(p*32 + c)*32 + jloc];
        h8 av = *(const h8*)&s.hsfull[b][c*8];
        acc = dot8(w, av, acc);
      }
      float xhv = acc + s.bhist_l[jloc];
      float xv = s.xt32[b][jloc], mv = s.mt32[b][jloc];
      loss += fabsf(xv - xhv) * mv * msumInv[t];
      float xcv = mv*xv + (1.0f - mv)*xhv;
      s.xh32[b][jloc] = xhv;
      xcb[(p*4 + b)*32 + jloc] = (_Float16)xcv;
    }
    __threadfence();
    __syncthreads();
    if (tid == 0) __hip_atomic_store(&fl[1*NP + p], tag, __ATOMIC_RELEASE, __HIP_MEMORY_SCOPE_AGENT);
    if (tid < NP){
      int cnt = 0;
      while (__hip_atomic_load(&fl[1*NP + tid], __ATOMIC_ACQUIRE, __HIP_MEMORY_SCOPE_AGENT) < tag
             && ++cnt < (1 << 27)) {}
    }
    __syncthreads();
    if (tid < 256){ // assemble xcfull: 256 dwords
      unsigned int v = ((const unsigned int*)xcb)[tid];
      int p2 = tid >> 6, b = (tid >> 4) & 3, qd = tid & 15;
      *(unsigned int*)&s.xcfull[b][32*p2 + 2*qd] = v;
    }
    __syncthreads();

    // ---- E: M3 z_h + epilogue (tid<128) ----
    if (tid < 128){
      int jloc = tid >> 2, b = tid & 3;
      float acc = 0.0f;
      #pragma unroll 4
      for (int c = 0; c < 16; ++c){
        h8 w = Pfeat[(p*16 + c)*32 + jloc];
        h8 av = *(const h8*)&s.xcfull[b][c*8];
        acc = dot8(w, av, acc);
      }
      float zhv = acc + s.bfeat_l[jloc];
      float xv = s.xt32[b][jloc], mv = s.mt32[b][jloc];
      float xhv = s.xh32[b][jloc], alv = s.al32[b][jloc];
      float e = (t < s.rn[b]) ? 1.0f : 0.0f;
      float inv = msumInv[t];
      float chv = alv*zhv + (1.0f - alv)*xhv;
      loss += fabsf(xv - zhv) * mv * e * inv;
      loss += fabsf(xv - chv) * mv * e * inv;
      float ccv = mv*xv + (1.0f - mv)*chv;
      out[((size_t)(b0 + b)*LT + t)*KT + 32*p + jloc] = ccv * e;
      ccb[(p*4 + b)*32 + jloc] = (_Float16)ccv;
    }
    __threadfence();
    __syncthreads();
    if (tid == 0) __hip_atomic_store(&fl[2*NP + p], tag, __ATOMIC_RELEASE, __HIP_MEMORY_SCOPE_AGENT);
    if (tid < NP){
      int cnt = 0;
      while (__hip_atomic_load(&fl[2*NP + tid], __ATOMIC_ACQUIRE, __HIP_MEMORY_SCOPE_AGENT) < tag
             && ++cnt < (1 << 27)) {}
    }
    __syncthreads();
    if (tid < 256){ // assemble ccm low half
      unsigned int v = ((const unsigned int*)ccb)[tid];
      int p2 = tid >> 6, b = (tid >> 4) & 3, qd = tid & 15;
      *(unsigned int*)&s.ccm[b][32*p2 + 2*qd] = v;
    }
    __syncthreads();

    // ---- G: M5 gi (tid<384) ----
    if (tid < 384){
      int jr = tid >> 1, bh = tid & 1;
      int bA = 2*bh, bB = 2*bh + 1;
      float a0 = 0.0f, a1 = 0.0f;
      #pragma unroll 4
      for (int c = 0; c < 32; ++c){
        h8 w = Pih[(p*32 + c)*192 + jr];
        h8 v0 = *(const h8*)&s.ccm[bA][c*8];
        h8 v1 = *(const h8*)&s.ccm[bB][c*8];
        a0 = dot8(w, v0, a0); a1 = dot8(w, v1, a1);
      }
      s.gi[jr][bA] = a0; s.gi[jr][bB] = a1;
    }
    __syncthreads();

    // ---- gates + h update (tid<256) ----
    if (tid < 256){
      int u = tid >> 2, b = tid & 3;
      float ir = s.gi[u][b]       + s.bih_l[u];
      float iz = s.gi[64 + u][b]  + s.bih_l[64 + u];
      float ig = s.gi[128 + u][b] + s.bih_l[128 + u];
      float hr = s.gh[u][b]       + s.bhh_l[u];
      float hz = s.gh[64 + u][b]  + s.bhh_l[64 + u];
      float hg = s.gh[128 + u][b] + s.bhh_l[128 + u];
      float r = sigf(ir + hr);
      float z = sigf(iz + hz);
      float n = tanh_fast(ig + r*hg);
      float hn = (1.0f - z)*n + z*s.hs32[b][u];
      if (t < s.rn[b]) s.h32[b][u] = hn;
    }
    __syncthreads();
  }

  // ---- loss reduction -> atomicAdd ----
  #pragma unroll
  for (int off = 32; off; off >>= 1) loss += __shfl_down(loss, off);
  if ((tid & 63) == 0) s.red[tid >> 6] = loss;
  __syncthreads();
  if (tid == 0){
    float tot = 0.0f;
    #pragma unroll
    for (int w = 0; w < 8; ++w) tot += s.red[w];
    atomicAdd(&out[LOSS_IDX], tot);
  }

  // ---- predictions: partial dot per part, exchange, part 0 finishes ----
  const int PTAG = LT + 1;
  if (tid < 4){
    int b = tid;
    float acc = 0.0f;
    #pragma unroll
    for (int u = 0; u < 64; ++u) acc += s.h32[b][u] * s.wout_l[u];
    prb[p*4 + b] = acc;
  }
  __threadfence();
  __syncthreads();
  if (tid == 0) __hip_atomic_store(&fl[3*NP + p], PTAG, __ATOMIC_RELEASE, __HIP_MEMORY_SCOPE_AGENT);
  if (p == 0){
    if (tid < NP){
      int cnt = 0;
      while (__hip_atomic_load(&fl[3*NP + tid], __ATOMIC_ACQUIRE, __HIP_MEMORY_SCOPE_AGENT) < PTAG
             && ++cnt < (1 << 27)) {}
    }
    __syncthreads();
    if (tid < 4){
      float sum = prb[0*4 + tid] + prb[1*4 + tid] + prb[2*4 + tid] + prb[3*4 + tid];
      out[PRED_IDX + b0 + tid] = sigf(sum + b_out[0]);
    }
  }
}

extern "C" void kernel_launch(void* const* d_in, const int* in_sizes, int n_in,
                              void* d_out, int out_size, void* d_ws, size_t ws_size,
                              hipStream_t stream){
  const float* x      = (const float*)d_in[0];
  const float* mask   = (const float*)d_in[1];
  const float* ts     = (const float*)d_in[2];
  const float* W_gh   = (const float*)d_in[3];
  const float* b_gh   = (const float*)d_in[4];
  const float* W_gx   = (const float*)d_in[5];
  const float* b_gx   = (const float*)d_in[6];
  const float* W_hist = (const float*)d_in[7];
  const float* b_hist = (const float*)d_in[8];
  const float* W_feat = (const float*)d_in[9];
  const float* b_feat = (const float*)d_in[10];
  const float* W_comb = (const float*)d_in[11];
  const float* b_comb = (const float*)d_in[12];
  const float* W_ih   = (const float*)d_in[13];
  const float* W_hh   = (const float*)d_in[14];
  const float* b_ih   = (const float*)d_in[15];
  const float* b_hh   = (const float*)d_in[16];
  const float* W_out  = (const float*)d_in[17];
  const float* b_out  = (const float*)d_in[18];
  const int*   rn     = (const int*)d_in[19];
  float* out = (float*)d_out;
  char* ws = (char*)d_ws;

  _Float16* Pgh   = (_Float16*)(ws + 0);        //  64 KB
  _Float16* Phist = (_Float16*)(ws + 65536);    //  64 KB
  _Float16* Pfeat = (_Float16*)(ws + 131072);   //  32 KB
  _Float16* Pcomb = (_Float16*)(ws + 163840);   //  64 KB
  _Float16* Pih   = (_Float16*)(ws + 229376);   // 384 KB
  _Float16* Phh   = (_Float16*)(ws + 622592);   // 384 KB
  _Float16* hsbuf = (_Float16*)(ws + 1015808);  // 128 KB
  _Float16* xcbuf = (_Float16*)(ws + 1146880);  //  64 KB
  _Float16* ccbuf = (_Float16*)(ws + 1212416);  //  64 KB
  float* predbuf  = (float*)(ws + 1277952);     //   4 KB
  int* flags      = (int*)(ws + 1282048);       //   4 KB
  float* msumInv  = (float*)(ws + 1286144);     //   1 KB
  float* gxd      = (float*)(ws + 1287168);     // 0.5 KB

  auto pk = [&](const float* src, _Float16* dst, int D, int Rp, int C, int gated, int zd){
    int total = NP*C*Rp;
    pack_part<<<dim3((total + 255)/256), dim3(256), 0, stream>>>(src, dst, D, Rp, C, gated, zd, total);
  };
  pk(W_gh,   Pgh,   128, 64,  16, 0, 0);
  pk(W_hist, Phist, 256, 32,  32, 0, 0);
  pk(W_feat, Pfeat, 128, 32,  16, 0, 1);
  pk(W_comb, Pcomb, 256, 32,  32, 0, 0);
  pk(W_ih,   Pih,   256, 192, 32, 1, 0);
  pk(W_hh,   Phh,   256, 192, 32, 1, 0);
  gxd_kernel<<<dim3(1), dim3(128), 0, stream>>>(W_gx, gxd);
  msum_kernel<<<dim3(LT), dim3(256), 0, stream>>>(mask, msumInv);
  hipMemsetAsync((void*)(out + LOSS_IDX), 0, sizeof(float), stream);

  rits_main<<<dim3(NG*NP), dim3(NT), 0, stream>>>(x, mask, ts,
      b_gh, b_gx, b_hist, b_feat, b_comb, b_ih, b_hh, W_out, b_out, rn,
      (const h8*)Pgh, (const h8*)Phist, (const h8*)Pfeat,
      (const h8*)Pcomb, (const h8*)Pih, (const h8*)Phh,
      gxd, msumInv, hsbuf, xcbuf, ccbuf, predbuf, flags, out);
}

// Round 4
// 2580.600 us; speedup vs baseline: 11.9504x; 11.9504x over previous
//
#include <hip/hip_runtime.h>
#include <math.h>

#define BT 256
#define LT 256
#define KT 128
#define HT 256
#define LOSS_IDX ((size_t)BT*LT*KT)
#define PRED_IDX (LOSS_IDX + 1)
#define LDP 1280   // P row: [gammah 256 | alpha 128 | gipre 768 | zpre 128] f16
#define GH0 0
#define AL0 256
#define GI0 384
#define ZP0 1152

typedef _Float16 h2 __attribute__((ext_vector_type(2)));
typedef _Float16 f16x8 __attribute__((ext_vector_type(8)));
typedef float f32x4 __attribute__((ext_vector_type(4)));

__device__ __forceinline__ float fd2(h2 a, h2 b, float c){
#if __has_builtin(__builtin_amdgcn_fdot2)
  return __builtin_amdgcn_fdot2(a, b, c, false);
#else
  return c + (float)a[0]*(float)b[0] + (float)a[1]*(float)b[1];
#endif
}
__device__ __forceinline__ float dot8(f16x8 w, f16x8 a, float acc){
  acc = fd2(__builtin_shufflevector(w,w,0,1), __builtin_shufflevector(a,a,0,1), acc);
  acc = fd2(__builtin_shufflevector(w,w,2,3), __builtin_shufflevector(a,a,2,3), acc);
  acc = fd2(__builtin_shufflevector(w,w,4,5), __builtin_shufflevector(a,a,4,5), acc);
  acc = fd2(__builtin_shufflevector(w,w,6,7), __builtin_shufflevector(a,a,6,7), acc);
  return acc;
}
__device__ __forceinline__ float sigf(float v){ return 1.0f/(1.0f + __expf(-v)); }
__device__ __forceinline__ float tanh_fast(float v){
  float a = fminf(fabsf(v), 15.0f);
  float e2 = __expf(2.0f*a);
  float r = (e2 - 1.0f)/(e2 + 1.0f);
  return copysignf(r, v);
}
__device__ __forceinline__ float f16bits(unsigned u, int hi){
  union { unsigned short s; _Float16 h; } c;
  c.s = (unsigned short)(hi ? (u >> 16) : (u & 0xffff));
  return (float)c.h;
}

// ---------- packing kernels ----------
__global__ void pack_cast(const float* __restrict__ src, _Float16* __restrict__ dst,
                          int J, int Kd, int diag, int total){
  int idx = blockIdx.x*256 + threadIdx.x;
  if (idx >= total) return;
  float v = src[idx];
  if (diag && (idx / Kd) == (idx % Kd)) v = 0.0f;
  dst[idx] = (_Float16)v;
}
// dst chunk-major: dst[(c*J + j)*8 + e] = src[j*K + c*8 + e]
__global__ void pack_rowchunks(const float* __restrict__ src, _Float16* __restrict__ dst,
                               int J, int K, int total){
  int idx = blockIdx.x*256 + threadIdx.x;
  if (idx >= total) return;
  int j = idx % J, c = idx / J;
  #pragma unroll
  for (int e = 0; e < 8; ++e)
    dst[(size_t)idx*8 + e] = (_Float16)src[(size_t)j*K + c*8 + e];
}
// col-major: dst[k*J + j] = src[j*ld + k], k<Kc
__global__ void pack_col(const float* __restrict__ src, _Float16* __restrict__ dst,
                         int J, int Kc, int ld, int diag, int total){
  int idx = blockIdx.x*256 + threadIdx.x;
  if (idx >= total) return;
  int j = idx % J, k = idx / J;
  float v = src[(size_t)j*ld + k];
  if (diag && j == k) v = 0.0f;
  dst[idx] = (_Float16)v;
}

// ---------- scan: deltas + GEMM inputs ----------
__global__ __launch_bounds__(128) void scan_kernel(
    const float* __restrict__ x, const float* __restrict__ mask, const float* __restrict__ ts,
    const float* __restrict__ W_gx, const float* __restrict__ b_gx,
    const int* __restrict__ record_num,
    _Float16* __restrict__ deltas, _Float16* __restrict__ Agx, _Float16* __restrict__ U)
{
  int b = blockIdx.x, k = threadIdx.x;
  int rn = record_num[b];
  float gxd = W_gx[(size_t)k*KT + k];
  float bgx = b_gx[k];
  float d = 1.0f, tsp = 0.0f;
  for (int t0 = 0; t0 < LT; t0 += 8){
    float xv[8], mv[8], tsv[8];
    #pragma unroll
    for (int u = 0; u < 8; ++u){
      size_t off = ((size_t)b*LT + t0 + u)*KT + k;
      xv[u] = x[off]; mv[u] = mask[off];
      tsv[u] = ts[(size_t)b*LT + t0 + u];
    }
    #pragma unroll
    for (int u = 0; u < 8; ++u){
      int t = t0 + u;
      if (t > 0){
        float gap = fabsf(tsv[u] - (u ? tsv[u-1] : tsp));
        d = gap + (1.0f - mv[u])*d;
      }
      float e = (t < rn) ? 1.0f : 0.0f;
      float dev = d * e;
      size_t row = (size_t)b*LT + t;
      deltas[row*KT + k] = (_Float16)dev;
      float gx = __expf(-fmaxf(fmaf(dev, gxd, bgx), 0.0f));
      Agx[row*2*KT + k]      = (_Float16)gx;
      Agx[row*2*KT + KT + k] = (_Float16)mv[u];
      U[row*2*KT + k]        = (_Float16)(mv[u]*xv[u]);
      U[row*2*KT + KT + k]   = (_Float16)mv[u];
    }
    tsp = tsv[7];
  }
}

__global__ void msum_kernel(const float* __restrict__ mask, float* __restrict__ msumInv){
  __shared__ float red[256];
  int t = blockIdx.x;
  float acc = 0.0f;
  for (int i = threadIdx.x; i < BT*KT; i += 256){
    int b = i >> 7, k = i & 127;
    acc += mask[((size_t)b*LT + t)*KT + k];
  }
  red[threadIdx.x] = acc; __syncthreads();
  for (int s = 128; s > 0; s >>= 1){
    if (threadIdx.x < s) red[threadIdx.x] += red[threadIdx.x + s];
    __syncthreads();
  }
  if (threadIdx.x == 0) msumInv[t] = 1.0f/(red[0] + 1e-5f);
}

// ---------- MFMA GEMM: C[M x N](f16, into P) = A[M x K] @ B^T, B rows = outputs ----------
// op: 0 none, 1 +bias, 2 exp(-relu(+bias))
__global__ __launch_bounds__(256) void gemm_f16(
    const _Float16* __restrict__ A, long ldA, int K,
    const _Float16* __restrict__ B, long ldB,
    _Float16* __restrict__ C, long colofs,
    const float* __restrict__ bias, int op)
{
  const int w = threadIdx.x >> 6, lane = threadIdx.x & 63;
  const int ml = lane & 15, quad = lane >> 4;
  const long m0 = (long)blockIdx.x*64 + w*16;
  const long nb0 = (long)blockIdx.y*64;
  f32x4 acc[4] = {{0,0,0,0},{0,0,0,0},{0,0,0,0},{0,0,0,0}};
  for (int kc = 0; kc < K; kc += 32){
    f16x8 a = *(const f16x8*)(A + (m0 + ml)*ldA + kc + quad*8);
    #pragma unroll
    for (int nt = 0; nt < 4; ++nt){
      f16x8 bfr = *(const f16x8*)(B + (nb0 + nt*16 + ml)*ldB + kc + quad*8);
      acc[nt] = __builtin_amdgcn_mfma_f32_16x16x32_f16(a, bfr, acc[nt], 0, 0, 0);
    }
  }
  #pragma unroll
  for (int nt = 0; nt < 4; ++nt){
    long col = nb0 + nt*16 + ml;
    float bv = (op >= 1) ? bias[col] : 0.0f;
    #pragma unroll
    for (int r = 0; r < 4; ++r){
      float v = acc[nt][r];
      if (op >= 1) v += bv;
      if (op == 2) v = __expf(-fmaxf(v, 0.0f));
      long row = m0 + quad*4 + r;
      C[row*LDP + colofs + col] = (_Float16)v;
    }
  }
}

// ---------- sequential recurrence: 1 block per batch ----------
#define NT 768

struct __align__(16) SeqS {
  float h[HT];
  float hs[HT];
  alignas(16) _Float16 hsh[HT];
  float gh[3*HT];
  float gi[3*HT];
  float xh[KT];
  float part[6][KT];
  float v3[KT], v5[KT];
  int lidx[KT];
  int posk[KT];
  int cnt;
  unsigned pb[2][LDP/2];
  float xb[2][KT], mb[2][KT];
  float bhist[KT], bfeat[KT];
  float bhh[3*HT];
  float wout[HT];
  float red[NT/64];
};

__global__ __launch_bounds__(NT, 1) void rits_seq(
    const float* __restrict__ x, const float* __restrict__ mask,
    const int* __restrict__ record_num, const float* __restrict__ msumInv,
    const _Float16* __restrict__ P,
    const f16x8* __restrict__ Whh_p, const f16x8* __restrict__ Whist_p,
    const _Float16* __restrict__ Wfc, const _Float16* __restrict__ Wihc,
    const float* __restrict__ b_hist, const float* __restrict__ b_feat,
    const float* __restrict__ b_hh,
    const float* __restrict__ W_out, const float* __restrict__ b_out,
    float* __restrict__ out)
{
  __shared__ SeqS s;
  const int tid = threadIdx.x;
  const int b = blockIdx.x;
  const int rn = record_num[b];
  const unsigned* __restrict__ Pd = (const unsigned*)P + (size_t)b*LT*(LDP/2);

  if (tid < HT) s.h[tid] = 0.0f;
  if (tid < KT){ s.bhist[tid] = b_hist[tid]; s.bfeat[tid] = b_feat[tid]; }
  if (tid < 3*HT) s.bhh[tid] = b_hh[tid];
  if (tid >= 256 && tid < 512) s.wout[tid - 256] = W_out[tid - 256];
  // preload t=0 streams
  if (tid < LDP/2) s.pb[0][tid] = Pd[tid];
  else if (tid < LDP/2 + KT){
    int k = tid - LDP/2;
    s.xb[0][k] = x[((size_t)b*LT)*KT + k];
    s.mb[0][k] = mask[((size_t)b*LT)*KT + k];
  }
  __syncthreads();

  float loss = 0.0f;

  for (int t = 0; t < LT; ++t){
    const int cur = t & 1, nxt = cur ^ 1;

    // prefetch next step's streams (no wait)
    unsigned pr0 = 0; float prx = 0.0f, prm = 0.0f;
    if (t < LT - 1){
      if (tid < LDP/2) pr0 = Pd[(size_t)(t+1)*(LDP/2) + tid];
      else if (tid < LDP/2 + KT){
        int k = tid - LDP/2;
        size_t off = ((size_t)b*LT + t + 1)*KT + k;
        prx = x[off]; prm = mask[off];
      }
    }

    // P1: hs = h * gamma_h
    if (tid == 0) s.cnt = 0;
    if (tid < HT){
      float g = f16bits(s.pb[cur][GH0/2 + (tid >> 1)], tid & 1);
      float hsv = s.h[tid] * g;
      s.hs[tid] = hsv;
      s.hsh[tid] = (_Float16)hsv;
    }
    __syncthreads();

    // P2: M6 gh (all 768) ; M2 x_h + loss1 + nnz list (tid<128)
    {
      const f16x8* hp = (const f16x8*)s.hsh;
      float acc = 0.0f;
      #pragma unroll 4
      for (int c = 0; c < 32; ++c)
        acc = dot8(Whh_p[c*768 + tid], hp[c], acc);
      s.gh[tid] = acc;
      if (tid < KT){
        float a2 = 0.0f;
        #pragma unroll 4
        for (int c = 0; c < 32; ++c)
          a2 = dot8(Whist_p[c*KT + tid], hp[c], a2);
        float xh = a2 + s.bhist[tid];
        s.xh[tid] = xh;
        float mv = s.mb[cur][tid], xv = s.xb[cur][tid];
        loss += fabsf(xv - xh) * mv * msumInv[t];
        if (mv == 0.0f){
          int pp = atomicAdd(&s.cnt, 1);
          s.lidx[pp] = tid; s.v3[pp] = xh; s.posk[tid] = pp;
        }
      }
    }
    __syncthreads();

    // P4a: sparse M3 strata
    {
      const int st = tid >> 7, j = tid & 127;
      const int c0 = s.cnt;
      float a = 0.0f;
      for (int i = st; i < c0; i += 6)
        a += s.v3[i] * (float)Wfc[s.lidx[i]*KT + j];
      s.part[st][j] = a;
    }
    __syncthreads();
    // P4b: z_h, c_h, losses, imputation, v5
    if (tid < KT){
      const int j = tid;
      float z = f16bits(s.pb[cur][ZP0/2 + (j >> 1)], j & 1) + s.bfeat[j]
              + s.part[0][j] + s.part[1][j] + s.part[2][j]
              + s.part[3][j] + s.part[4][j] + s.part[5][j];
      float al = f16bits(s.pb[cur][AL0/2 + (j >> 1)], j & 1);
      float xh = s.xh[j];
      float mv = s.mb[cur][j], xv = s.xb[cur][j];
      float e = (t < rn) ? 1.0f : 0.0f;
      float inv = msumInv[t];
      float ch = al*z + (1.0f - al)*xh;
      loss += (fabsf(xv - z) + fabsf(xv - ch)) * mv * e * inv;
      float cc = mv*xv + (1.0f - mv)*ch;
      out[((size_t)b*LT + t)*KT + j] = cc * e;
      if (mv == 0.0f) s.v5[s.posk[j]] = ch;
    }
    __syncthreads();

    // P5: sparse M5 -> gi
    {
      const int c0 = s.cnt;
      float g = f16bits(s.pb[cur][GI0/2 + (tid >> 1)], tid & 1);
      for (int i = 0; i < c0; ++i)
        g += s.v5[i] * (float)Wihc[s.lidx[i]*768 + tid];
      s.gi[tid] = g;
    }
    __syncthreads();

    // P6: gates + h update ; stream writeback
    if (tid < HT){
      const int j = tid;
      float ir = s.gi[j],        iz = s.gi[HT + j],        ig = s.gi[2*HT + j];
      float hr = s.gh[j] + s.bhh[j];
      float hz = s.gh[HT + j] + s.bhh[HT + j];
      float hg = s.gh[2*HT + j] + s.bhh[2*HT + j];
      float r = sigf(ir + hr);
      float zg = sigf(iz + hz);
      float n = tanh_fast(ig + r*hg);
      float hn = (1.0f - zg)*n + zg*s.hs[j];
      if (t < rn) s.h[j] = hn;
    }
    if (t < LT - 1){
      if (tid < LDP/2) s.pb[nxt][tid] = pr0;
      else if (tid < LDP/2 + KT){
        int k = tid - LDP/2;
        s.xb[nxt][k] = prx; s.mb[nxt][k] = prm;
      }
    }
    __syncthreads();
  }

  // loss reduction
  #pragma unroll
  for (int off = 32; off; off >>= 1) loss += __shfl_down(loss, off);
  if ((tid & 63) == 0) s.red[tid >> 6] = loss;
  __syncthreads();
  if (tid == 0){
    float tot = 0.0f;
    #pragma unroll
    for (int w = 0; w < NT/64; ++w) tot += s.red[w];
    atomicAdd(&out[LOSS_IDX], tot);
  }

  // prediction
  if (tid < HT) s.part[0][tid & 127] = 0.0f; // scratch not needed; do tree in gh
  if (tid < HT) s.gh[tid] = s.h[tid] * s.wout[tid];
  __syncthreads();
  for (int st2 = 128; st2 > 0; st2 >>= 1){
    if (tid < st2) s.gh[tid] += s.gh[tid + st2];
    __syncthreads();
  }
  if (tid == 0) out[PRED_IDX + b] = sigf(s.gh[0] + b_out[0]);
}

extern "C" void kernel_launch(void* const* d_in, const int* in_sizes, int n_in,
                              void* d_out, int out_size, void* d_ws, size_t ws_size,
                              hipStream_t stream){
  const float* x      = (const float*)d_in[0];
  const float* mask   = (const float*)d_in[1];
  const float* ts     = (const float*)d_in[2];
  const float* W_gh   = (const float*)d_in[3];
  const float* b_gh   = (const float*)d_in[4];
  const float* W_gx   = (const float*)d_in[5];
  const float* b_gx   = (const float*)d_in[6];
  const float* W_hist = (const float*)d_in[7];
  const float* b_hist = (const float*)d_in[8];
  const float* W_feat = (const float*)d_in[9];
  const float* b_feat = (const float*)d_in[10];
  const float* W_comb = (const float*)d_in[11];
  const float* b_comb = (const float*)d_in[12];
  const float* W_ih   = (const float*)d_in[13];
  const float* W_hh   = (const float*)d_in[14];
  const float* b_ih   = (const float*)d_in[15];
  const float* b_hh   = (const float*)d_in[16];
  const float* W_out  = (const float*)d_in[17];
  const float* b_out  = (const float*)d_in[18];
  const int*   rn     = (const int*)d_in[19];
  float* out = (float*)d_out;
  char* ws = (char*)d_ws;

  size_t off = 0;
  auto alloc = [&](size_t bytes) -> char* {
    char* p = ws + off;
    off += (bytes + 255) & ~(size_t)255;
    return p;
  };
  _Float16* P      = (_Float16*)alloc((size_t)BT*LT*LDP*2);   // 167.8 MB
  _Float16* deltas = (_Float16*)alloc((size_t)BT*LT*KT*2);    // 16.8 MB
  _Float16* Agx    = (_Float16*)alloc((size_t)BT*LT*2*KT*2);  // 33.6 MB
  _Float16* U      = (_Float16*)alloc((size_t)BT*LT*2*KT*2);  // 33.6 MB
  _Float16* WghF   = (_Float16*)alloc(HT*KT*2);
  _Float16* WcombF = (_Float16*)alloc(KT*2*KT*2);
  _Float16* WihF   = (_Float16*)alloc(3*HT*2*KT*2);
  _Float16* WfeatF = (_Float16*)alloc(KT*KT*2);
  _Float16* Whh_p  = (_Float16*)alloc(3*HT*HT*2);
  _Float16* Whist_p= (_Float16*)alloc(KT*HT*2);
  _Float16* Wfc    = (_Float16*)alloc(KT*KT*2);
  _Float16* Wihc   = (_Float16*)alloc(KT*3*HT*2);
  float* msumInv   = (float*)alloc(LT*4);

  auto grid1 = [](int n){ return dim3((n + 255)/256); };
  // GEMM-B casts (row-major f16)
  pack_cast<<<grid1(HT*KT), 256, 0, stream>>>(W_gh, WghF, HT, KT, 0, HT*KT);
  pack_cast<<<grid1(KT*2*KT), 256, 0, stream>>>(W_comb, WcombF, KT, 2*KT, 0, KT*2*KT);
  pack_cast<<<grid1(3*HT*2*KT), 256, 0, stream>>>(W_ih, WihF, 3*HT, 2*KT, 0, 3*HT*2*KT);
  pack_cast<<<grid1(KT*KT), 256, 0, stream>>>(W_feat, WfeatF, KT, KT, 1, KT*KT);
  // sequential-phase packs
  pack_rowchunks<<<grid1(3*HT*(HT/8)), 256, 0, stream>>>(W_hh, Whh_p, 3*HT, HT, 3*HT*(HT/8));
  pack_rowchunks<<<grid1(KT*(HT/8)), 256, 0, stream>>>(W_hist, Whist_p, KT, HT, KT*(HT/8));
  pack_col<<<grid1(KT*KT), 256, 0, stream>>>(W_feat, Wfc, KT, KT, KT, 1, KT*KT);
  pack_col<<<grid1(768*KT), 256, 0, stream>>>(W_ih, Wihc, 3*HT, KT, 2*KT, 0, 3*HT*KT);

  scan_kernel<<<dim3(BT), dim3(KT), 0, stream>>>(x, mask, ts, W_gx, b_gx, rn, deltas, Agx, U);
  msum_kernel<<<dim3(LT), dim3(256), 0, stream>>>(mask, msumInv);

  const int MR = BT*LT;  // 65536 rows
  // G1: gamma_h = exp(-relu(deltas @ Wgh^T + b_gh))
  gemm_f16<<<dim3(MR/64, HT/64), 256, 0, stream>>>(deltas, KT, KT, WghF, KT, P, GH0, b_gh, 2);
  // G2: alpha = [gx|m] @ Wcomb^T + b_comb
  gemm_f16<<<dim3(MR/64, KT/64), 256, 0, stream>>>(Agx, 2*KT, 2*KT, WcombF, 2*KT, P, AL0, b_comb, 1);
  // G3: gi_pre = [mx|m] @ Wih^T + b_ih
  gemm_f16<<<dim3(MR/64, 3*HT/64), 256, 0, stream>>>(U, 2*KT, 2*KT, WihF, 2*KT, P, GI0, b_ih, 1);
  // G4: zpre = (mx) @ Wfeat_m^T
  gemm_f16<<<dim3(MR/64, KT/64), 256, 0, stream>>>(U, 2*KT, KT, WfeatF, KT, P, ZP0, (const float*)nullptr, 0);

  hipMemsetAsync((void*)(out + LOSS_IDX), 0, sizeof(float), stream);

  rits_seq<<<dim3(BT), dim3(NT), 0, stream>>>(x, mask, rn, msumInv, P,
      (const f16x8*)Whh_p, (const f16x8*)Whist_p, Wfc, Wihc,
      b_hist, b_feat, b_hh, W_out, b_out, out);
}

// Round 5
// 2419.975 us; speedup vs baseline: 12.7436x; 1.0664x over previous
//
#include <hip/hip_runtime.h>
#include <math.h>

#define BT 256
#define LT 256
#define KT 128
#define HT 256
#define LOSS_IDX ((size_t)BT*LT*KT)
#define PRED_IDX (LOSS_IDX + 1)
#define LDP 1280   // P row: [gammah 256 | alpha 128 | gipre 768 | zpre 128] f16
#define GH0 0
#define AL0 256
#define GI0 384
#define ZP0 1152

typedef _Float16 h2 __attribute__((ext_vector_type(2)));
typedef _Float16 f16x8 __attribute__((ext_vector_type(8)));
typedef float f32x4 __attribute__((ext_vector_type(4)));

__device__ __forceinline__ float fd2(h2 a, h2 b, float c){
#if __has_builtin(__builtin_amdgcn_fdot2)
  return __builtin_amdgcn_fdot2(a, b, c, false);
#else
  return c + (float)a[0]*(float)b[0] + (float)a[1]*(float)b[1];
#endif
}
__device__ __forceinline__ float dot8(f16x8 w, f16x8 a, float acc){
  acc = fd2(__builtin_shufflevector(w,w,0,1), __builtin_shufflevector(a,a,0,1), acc);
  acc = fd2(__builtin_shufflevector(w,w,2,3), __builtin_shufflevector(a,a,2,3), acc);
  acc = fd2(__builtin_shufflevector(w,w,4,5), __builtin_shufflevector(a,a,4,5), acc);
  acc = fd2(__builtin_shufflevector(w,w,6,7), __builtin_shufflevector(a,a,6,7), acc);
  return acc;
}
__device__ __forceinline__ float sigf(float v){ return 1.0f/(1.0f + __expf(-v)); }
__device__ __forceinline__ float tanh_fast(float v){
  float a = fminf(fabsf(v), 15.0f);
  float e2 = __expf(2.0f*a);
  float r = (e2 - 1.0f)/(e2 + 1.0f);
  return copysignf(r, v);
}
__device__ __forceinline__ float f16bits(unsigned u, int hi){
  union { unsigned short s; _Float16 h; } c;
  c.s = (unsigned short)(hi ? (u >> 16) : (u & 0xffff));
  return (float)c.h;
}

// ---------- packing kernels ----------
__global__ void pack_cast(const float* __restrict__ src, _Float16* __restrict__ dst,
                          int J, int Kd, int diag, int total){
  int idx = blockIdx.x*256 + threadIdx.x;
  if (idx >= total) return;
  float v = src[idx];
  if (diag && (idx / Kd) == (idx % Kd)) v = 0.0f;
  dst[idx] = (_Float16)v;
}
__global__ void pack_rowchunks(const float* __restrict__ src, _Float16* __restrict__ dst,
                               int J, int K, int total){
  int idx = blockIdx.x*256 + threadIdx.x;
  if (idx >= total) return;
  int j = idx % J, c = idx / J;
  #pragma unroll
  for (int e = 0; e < 8; ++e)
    dst[(size_t)idx*8 + e] = (_Float16)src[(size_t)j*K + c*8 + e];
}
__global__ void pack_col(const float* __restrict__ src, _Float16* __restrict__ dst,
                         int J, int Kc, int ld, int diag, int total){
  int idx = blockIdx.x*256 + threadIdx.x;
  if (idx >= total) return;
  int j = idx % J, k = idx / J;
  float v = src[(size_t)j*ld + k];
  if (diag && j == k) v = 0.0f;
  dst[idx] = (_Float16)v;
}

// ---------- scan: deltas + GEMM inputs ----------
__global__ __launch_bounds__(128) void scan_kernel(
    const float* __restrict__ x, const float* __restrict__ mask, const float* __restrict__ ts,
    const float* __restrict__ W_gx, const float* __restrict__ b_gx,
    const int* __restrict__ record_num,
    _Float16* __restrict__ deltas, _Float16* __restrict__ Agx, _Float16* __restrict__ U)
{
  int b = blockIdx.x, k = threadIdx.x;
  int rn = record_num[b];
  float gxd = W_gx[(size_t)k*KT + k];
  float bgx = b_gx[k];
  float d = 1.0f, tsp = 0.0f;
  for (int t0 = 0; t0 < LT; t0 += 8){
    float xv[8], mv[8], tsv[8];
    #pragma unroll
    for (int u = 0; u < 8; ++u){
      size_t off = ((size_t)b*LT + t0 + u)*KT + k;
      xv[u] = x[off]; mv[u] = mask[off];
      tsv[u] = ts[(size_t)b*LT + t0 + u];
    }
    #pragma unroll
    for (int u = 0; u < 8; ++u){
      int t = t0 + u;
      if (t > 0){
        float gap = fabsf(tsv[u] - (u ? tsv[u-1] : tsp));
        d = gap + (1.0f - mv[u])*d;
      }
      float e = (t < rn) ? 1.0f : 0.0f;
      float dev = d * e;
      size_t row = (size_t)b*LT + t;
      deltas[row*KT + k] = (_Float16)dev;
      float gx = __expf(-fmaxf(fmaf(dev, gxd, bgx), 0.0f));
      Agx[row*2*KT + k]      = (_Float16)gx;
      Agx[row*2*KT + KT + k] = (_Float16)mv[u];
      U[row*2*KT + k]        = (_Float16)(mv[u]*xv[u]);
      U[row*2*KT + KT + k]   = (_Float16)mv[u];
    }
    tsp = tsv[7];
  }
}

__global__ void msum_kernel(const float* __restrict__ mask, float* __restrict__ msumInv){
  __shared__ float red[256];
  int t = blockIdx.x;
  float acc = 0.0f;
  for (int i = threadIdx.x; i < BT*KT; i += 256){
    int b = i >> 7, k = i & 127;
    acc += mask[((size_t)b*LT + t)*KT + k];
  }
  red[threadIdx.x] = acc; __syncthreads();
  for (int s = 128; s > 0; s >>= 1){
    if (threadIdx.x < s) red[threadIdx.x] += red[threadIdx.x + s];
    __syncthreads();
  }
  if (threadIdx.x == 0) msumInv[t] = 1.0f/(red[0] + 1e-5f);
}

// ---------- MFMA GEMM ----------
__global__ __launch_bounds__(256) void gemm_f16(
    const _Float16* __restrict__ A, long ldA, int K,
    const _Float16* __restrict__ B, long ldB,
    _Float16* __restrict__ C, long colofs,
    const float* __restrict__ bias, int op)
{
  const int w = threadIdx.x >> 6, lane = threadIdx.x & 63;
  const int ml = lane & 15, quad = lane >> 4;
  const long m0 = (long)blockIdx.x*64 + w*16;
  const long nb0 = (long)blockIdx.y*64;
  f32x4 acc[4] = {{0,0,0,0},{0,0,0,0},{0,0,0,0},{0,0,0,0}};
  for (int kc = 0; kc < K; kc += 32){
    f16x8 a = *(const f16x8*)(A + (m0 + ml)*ldA + kc + quad*8);
    #pragma unroll
    for (int nt = 0; nt < 4; ++nt){
      f16x8 bfr = *(const f16x8*)(B + (nb0 + nt*16 + ml)*ldB + kc + quad*8);
      acc[nt] = __builtin_amdgcn_mfma_f32_16x16x32_f16(a, bfr, acc[nt], 0, 0, 0);
    }
  }
  #pragma unroll
  for (int nt = 0; nt < 4; ++nt){
    long col = nb0 + nt*16 + ml;
    float bv = (op >= 1) ? bias[col] : 0.0f;
    #pragma unroll
    for (int r = 0; r < 4; ++r){
      float v = acc[nt][r];
      if (op >= 1) v += bv;
      if (op == 2) v = __expf(-fmaxf(v, 0.0f));
      long row = m0 + quad*4 + r;
      C[row*LDP + colofs + col] = (_Float16)v;
    }
  }
}

// ---------- sequential recurrence: 1 block per batch ----------
#define NT 768

struct __align__(16) SeqS {
  f16x8 whist_l[32*128];        // 64 KB, [c*128 + j]
  _Float16 wfc_l[128*128];      // 32 KB, [k*128 + j]
  float h[HT];
  float hs[HT];
  alignas(16) _Float16 hsh[HT];
  float gh[3*HT];
  float gi[3*HT];
  float xh[KT];
  float part6[6][KT];
  float v3[KT], v5[KT];
  int lidx[136];
  int posk[KT];
  int cnt;
  unsigned pb[2][LDP/2];
  float xb[2][KT], mb[2][KT];
  float bhist[KT], bfeat[KT];
  float bhh[3*HT];
  float wout[HT];
  float minv[LT];
  float red[NT/64];
};

__global__ __launch_bounds__(NT, 1) void rits_seq(
    const float* __restrict__ x, const float* __restrict__ mask,
    const int* __restrict__ record_num, const float* __restrict__ msumInv,
    const _Float16* __restrict__ P,
    const f16x8* __restrict__ Whh_p, const f16x8* __restrict__ Whist_p,
    const _Float16* __restrict__ Wfc, const _Float16* __restrict__ Wihc,
    const float* __restrict__ b_hist, const float* __restrict__ b_feat,
    const float* __restrict__ b_hh,
    const float* __restrict__ W_out, const float* __restrict__ b_out,
    float* __restrict__ out)
{
  __shared__ SeqS s;
  const int tid = threadIdx.x;
  const int b = blockIdx.x;
  const int rn = record_num[b];
  const unsigned* __restrict__ Pd = (const unsigned*)P + (size_t)b*LT*(LDP/2);

  // ---- init: LDS-resident weights + constants ----
  for (int i = tid; i < 32*128; i += NT) s.whist_l[i] = Whist_p[i];
  for (int i = tid; i < 128*128/2; i += NT)
    ((unsigned*)s.wfc_l)[i] = ((const unsigned*)Wfc)[i];
  if (tid < HT) s.h[tid] = 0.0f;
  if (tid < KT){ s.bhist[tid] = b_hist[tid]; s.bfeat[tid] = b_feat[tid]; }
  if (tid < 3*HT) s.bhh[tid] = b_hh[tid];
  if (tid < 136) s.lidx[tid] = 0;
  if (tid >= 256 && tid < 512) s.wout[tid - 256] = W_out[tid - 256];
  if (tid >= 512 && tid < 512 + LT) s.minv[tid - 512] = msumInv[tid - 512];
  // preload t=0 streams
  if (tid < LDP/2) s.pb[0][tid] = Pd[tid];
  else if (tid < LDP/2 + KT){
    int k = tid - LDP/2;
    s.xb[0][k] = x[((size_t)b*LT)*KT + k];
    s.mb[0][k] = mask[((size_t)b*LT)*KT + k];
  }
  __syncthreads();

  float loss = 0.0f;

  for (int t = 0; t < LT; ++t){
    const int cur = t & 1, nxt = cur ^ 1;

    // ---- P1: hs = h*gamma_h ; issue next-step prefetch ----
    unsigned pr0 = 0; float prx = 0.0f, prm = 0.0f;
    if (t < LT - 1){
      if (tid < LDP/2) pr0 = Pd[(size_t)(t+1)*(LDP/2) + tid];
      else {
        int k = tid - LDP/2;
        size_t offx = ((size_t)b*LT + t + 1)*KT + k;
        prx = x[offx]; prm = mask[offx];
      }
    }
    if (tid == 0) s.cnt = 0;
    if (tid < HT){
      float g = f16bits(s.pb[cur][tid >> 1], tid & 1);
      float hsv = s.h[tid] * g;
      s.hs[tid] = hsv;
      s.hsh[tid] = (_Float16)hsv;
    }
    __syncthreads();

    // ---- A: gh (all 768, global Whh) + xh/loss1/list (tid<128, LDS Whist) ----
    {
      const f16x8* hp = (const f16x8*)s.hsh;
      if (tid < KT){
        float a2 = 0.0f;
        #pragma unroll 8
        for (int c = 0; c < 32; ++c)
          a2 = dot8(s.whist_l[c*128 + tid], hp[c], a2);
        float xh = a2 + s.bhist[tid];
        s.xh[tid] = xh;
        float mv = s.mb[cur][tid], xv = s.xb[cur][tid];
        loss += fabsf(xv - xh) * mv * s.minv[t];
        if (mv == 0.0f){
          int pp = atomicAdd(&s.cnt, 1);
          s.lidx[pp] = tid; s.v3[pp] = xh; s.posk[tid] = pp;
        }
      }
      float acc = 0.0f;
      #pragma unroll 8
      for (int c = 0; c < 32; ++c)
        acc = dot8(Whh_p[c*768 + tid], hp[c], acc);
      s.gh[tid] = acc;
    }
    __syncthreads();

    // ---- C: zh strata (LDS Wfc) + prefetch Wihc sparse columns ----
    const int c0 = s.cnt;
    const int c4 = (c0 + 7) & ~7;
    {
      int st = tid >> 7, j = tid & 127;
      float a = 0.0f;
      for (int i = st; i < c0; i += 6)
        a += s.v3[i] * (float)s.wfc_l[s.lidx[i]*128 + j];
      s.part6[st][j] = a;
    }
    float wpre[16];
    #pragma unroll
    for (int u = 0; u < 16; ++u)
      wpre[u] = (u < c4) ? (float)Wihc[(size_t)s.lidx[u]*768 + tid] : 0.0f;
    __syncthreads();

    // ---- D: z_h, c_h, losses, imputation, v5 (tid<128) ----
    if (tid < KT){
      const int j = tid;
      if (j >= c0 && j < c4) s.v5[j] = 0.0f;
      float z = f16bits(s.pb[cur][ZP0/2 + (j >> 1)], j & 1) + s.bfeat[j]
              + s.part6[0][j] + s.part6[1][j] + s.part6[2][j]
              + s.part6[3][j] + s.part6[4][j] + s.part6[5][j];
      float al = f16bits(s.pb[cur][AL0/2 + (j >> 1)], j & 1);
      float xh = s.xh[j];
      float mv = s.mb[cur][j], xv = s.xb[cur][j];
      float e = (t < rn) ? 1.0f : 0.0f;
      float inv = s.minv[t];
      float ch = al*z + (1.0f - al)*xh;
      loss += (fabsf(xv - z) + fabsf(xv - ch)) * mv * e * inv;
      float cc = mv*xv + (1.0f - mv)*ch;
      out[((size_t)b*LT + t)*KT + j] = cc * e;
      if (mv == 0.0f) s.v5[s.posk[j]] = ch;
    }
    __syncthreads();

    // ---- E: sparse M5 -> gi (prefetched head + unrolled tail) ----
    {
      float g = f16bits(s.pb[cur][GI0/2 + (tid >> 1)], tid & 1);
      #pragma unroll
      for (int u = 0; u < 16; ++u)
        if (u < c4) g += s.v5[u] * wpre[u];
      for (int i = 16; i < c4; i += 8){
        #pragma unroll
        for (int u = 0; u < 8; ++u)
          g += s.v5[i + u] * (float)Wihc[(size_t)s.lidx[i + u]*768 + tid];
      }
      s.gi[tid] = g;
    }
    __syncthreads();

    // ---- F: gates + h update ; stage prefetched buffers ----
    if (tid < HT){
      const int j = tid;
      float ir = s.gi[j], iz = s.gi[HT + j], ig = s.gi[2*HT + j];
      float hr = s.gh[j] + s.bhh[j];
      float hz = s.gh[HT + j] + s.bhh[HT + j];
      float hg = s.gh[2*HT + j] + s.bhh[2*HT + j];
      float r = sigf(ir + hr);
      float zg = sigf(iz + hz);
      float n = tanh_fast(ig + r*hg);
      float hn = (1.0f - zg)*n + zg*s.hs[j];
      if (t < rn) s.h[j] = hn;
    }
    if (t < LT - 1){
      if (tid < LDP/2) s.pb[nxt][tid] = pr0;
      else {
        int k = tid - LDP/2;
        s.xb[nxt][k] = prx; s.mb[nxt][k] = prm;
      }
    }
    __syncthreads();
  }

  // ---- loss reduction ----
  #pragma unroll
  for (int off = 32; off; off >>= 1) loss += __shfl_down(loss, off);
  if ((tid & 63) == 0) s.red[tid >> 6] = loss;
  __syncthreads();
  if (tid == 0){
    float tot = 0.0f;
    #pragma unroll
    for (int w = 0; w < NT/64; ++w) tot += s.red[w];
    atomicAdd(&out[LOSS_IDX], tot);
  }

  // ---- prediction ----
  if (tid < HT) s.gh[tid] = s.h[tid] * s.wout[tid];
  __syncthreads();
  for (int st2 = 128; st2 > 0; st2 >>= 1){
    if (tid < st2) s.gh[tid] += s.gh[tid + st2];
    __syncthreads();
  }
  if (tid == 0) out[PRED_IDX + b] = sigf(s.gh[0] + b_out[0]);
}

extern "C" void kernel_launch(void* const* d_in, const int* in_sizes, int n_in,
                              void* d_out, int out_size, void* d_ws, size_t ws_size,
                              hipStream_t stream){
  const float* x      = (const float*)d_in[0];
  const float* mask   = (const float*)d_in[1];
  const float* ts     = (const float*)d_in[2];
  const float* W_gh   = (const float*)d_in[3];
  const float* b_gh   = (const float*)d_in[4];
  const float* W_gx   = (const float*)d_in[5];
  const float* b_gx   = (const float*)d_in[6];
  const float* W_hist = (const float*)d_in[7];
  const float* b_hist = (const float*)d_in[8];
  const float* W_feat = (const float*)d_in[9];
  const float* b_feat = (const float*)d_in[10];
  const float* W_comb = (const float*)d_in[11];
  const float* b_comb = (const float*)d_in[12];
  const float* W_ih   = (const float*)d_in[13];
  const float* W_hh   = (const float*)d_in[14];
  const float* b_ih   = (const float*)d_in[15];
  const float* b_hh   = (const float*)d_in[16];
  const float* W_out  = (const float*)d_in[17];
  const float* b_out  = (const float*)d_in[18];
  const int*   rn     = (const int*)d_in[19];
  float* out = (float*)d_out;
  char* ws = (char*)d_ws;

  size_t off = 0;
  auto alloc = [&](size_t bytes) -> char* {
    char* p = ws + off;
    off += (bytes + 255) & ~(size_t)255;
    return p;
  };
  _Float16* P      = (_Float16*)alloc((size_t)BT*LT*LDP*2);   // 167.8 MB
  _Float16* deltas = (_Float16*)alloc((size_t)BT*LT*KT*2);    // 16.8 MB
  _Float16* Agx    = (_Float16*)alloc((size_t)BT*LT*2*KT*2);  // 33.6 MB
  _Float16* U      = (_Float16*)alloc((size_t)BT*LT*2*KT*2);  // 33.6 MB
  _Float16* WghF   = (_Float16*)alloc(HT*KT*2);
  _Float16* WcombF = (_Float16*)alloc(KT*2*KT*2);
  _Float16* WihF   = (_Float16*)alloc(3*HT*2*KT*2);
  _Float16* WfeatF = (_Float16*)alloc(KT*KT*2);
  _Float16* Whh_p  = (_Float16*)alloc(3*HT*HT*2);
  _Float16* Whist_p= (_Float16*)alloc(KT*HT*2);
  _Float16* Wfc    = (_Float16*)alloc(KT*KT*2);
  _Float16* Wihc   = (_Float16*)alloc(KT*3*HT*2);
  float* msumInv   = (float*)alloc(LT*4);

  auto grid1 = [](int n){ return dim3((n + 255)/256); };
  pack_cast<<<grid1(HT*KT), 256, 0, stream>>>(W_gh, WghF, HT, KT, 0, HT*KT);
  pack_cast<<<grid1(KT*2*KT), 256, 0, stream>>>(W_comb, WcombF, KT, 2*KT, 0, KT*2*KT);
  pack_cast<<<grid1(3*HT*2*KT), 256, 0, stream>>>(W_ih, WihF, 3*HT, 2*KT, 0, 3*HT*2*KT);
  pack_cast<<<grid1(KT*KT), 256, 0, stream>>>(W_feat, WfeatF, KT, KT, 1, KT*KT);
  pack_rowchunks<<<grid1(3*HT*(HT/8)), 256, 0, stream>>>(W_hh, Whh_p, 3*HT, HT, 3*HT*(HT/8));
  pack_rowchunks<<<grid1(KT*(HT/8)), 256, 0, stream>>>(W_hist, Whist_p, KT, HT, KT*(HT/8));
  pack_col<<<grid1(KT*KT), 256, 0, stream>>>(W_feat, Wfc, KT, KT, KT, 1, KT*KT);
  pack_col<<<grid1(768*KT), 256, 0, stream>>>(W_ih, Wihc, 3*HT, KT, 2*KT, 0, 3*HT*KT);

  scan_kernel<<<dim3(BT), dim3(KT), 0, stream>>>(x, mask, ts, W_gx, b_gx, rn, deltas, Agx, U);
  msum_kernel<<<dim3(LT), dim3(256), 0, stream>>>(mask, msumInv);

  const int MR = BT*LT;
  gemm_f16<<<dim3(MR/64, HT/64), 256, 0, stream>>>(deltas, KT, KT, WghF, KT, P, GH0, b_gh, 2);
  gemm_f16<<<dim3(MR/64, KT/64), 256, 0, stream>>>(Agx, 2*KT, 2*KT, WcombF, 2*KT, P, AL0, b_comb, 1);
  gemm_f16<<<dim3(MR/64, 3*HT/64), 256, 0, stream>>>(U, 2*KT, 2*KT, WihF, 2*KT, P, GI0, b_ih, 1);
  gemm_f16<<<dim3(MR/64, KT/64), 256, 0, stream>>>(U, 2*KT, KT, WfeatF, KT, P, ZP0, (const float*)nullptr, 0);

  hipMemsetAsync((void*)(out + LOSS_IDX), 0, sizeof(float), stream);

  rits_seq<<<dim3(BT), dim3(NT), 0, stream>>>(x, mask, rn, msumInv, P,
      (const f16x8*)Whh_p, (const f16x8*)Whist_p, Wfc, Wihc,
      b_hist, b_feat, b_hh, W_out, b_out, out);
}